// Round 6
// baseline (618.350 us; speedup 1.0000x reference)
//
#include <hip/hip_runtime.h>
#include <hip/hip_bf16.h>

#define BB 4
#define TT 2048
#define CC 2048
#define NH 16
#define HD 128
#define BT (BB*TT)   // 8192

using u16 = unsigned short;
typedef __bf16 bf16x8 __attribute__((ext_vector_type(8)));
typedef float  f32x4  __attribute__((ext_vector_type(4)));

#define AS1 __attribute__((address_space(1)))
#define AS3 __attribute__((address_space(3)))

__device__ __forceinline__ float b2f(u16 u){ return __uint_as_float(((unsigned)u) << 16); }
__device__ __forceinline__ u16 f2b(float f){
  unsigned u = __float_as_uint(f);
  u += 0x7FFFu + ((u >> 16) & 1u);
  return (u16)(u >> 16);
}
__device__ __forceinline__ void gld_lds16(const u16* g, u16* l){
  __builtin_amdgcn_global_load_lds((const AS1 void*)g, (AS3 void*)l, 16, 0, 0);
}

// ---------------- fp32 -> bf16 convert ----------------
__global__ __launch_bounds__(256) void cvt_kernel(const float* __restrict__ in,
                                                  u16* __restrict__ out, int n8)
{
  const int i = blockIdx.x * 256 + threadIdx.x;
  if (i >= n8) return;
  const float4 a = ((const float4*)in)[2*i];
  const float4 b = ((const float4*)in)[2*i + 1];
  uint4 pk;
  pk.x = (unsigned)f2b(a.x) | ((unsigned)f2b(a.y) << 16);
  pk.y = (unsigned)f2b(a.z) | ((unsigned)f2b(a.w) << 16);
  pk.z = (unsigned)f2b(b.x) | ((unsigned)f2b(b.y) << 16);
  pk.w = (unsigned)f2b(b.z) | ((unsigned)f2b(b.w) << 16);
  ((uint4*)out)[i] = pk;
}

// ---------------- 256x256 ring-4 software-pipelined MFMA GEMM ----------------
// R5/R6: QKV fused via blockIdx.z (W panel stride wz, output stride cz). The
// z-slices are 256 blocks each (256 % 8 == 0 -> XCD swizzle alignment holds
// per slice); round-robin dispatch puts (y,x,z) and (y,x,z+1) on the same
// XCD, so the per-XCD A-stripe read in the z=0 round can be L2/LLC resident
// for z=1,2 (A is shared across Q/K/V).
// Schedule = R4: ring-4 LDS (BK=32), distance-3 staging, counted vmcnt
// boundaries, cross-tile register fragment prefetch, one barrier per tile.
template<bool OUT_BF16>
__global__ __launch_bounds__(512, 2) void gemm256(const u16* __restrict__ A,
                                                  const u16* __restrict__ W,
                                                  void* __restrict__ Cv,
                                                  int K, int N,
                                                  long wz, long cz)
{
  __shared__ u16 lds[65536];  // 131072 B
  const int tid  = threadIdx.x;
  const int lane = tid & 63;
  const int wid  = tid >> 6;
  const int wm   = wid >> 2;   // 0..1
  const int wn   = wid & 3;    // 0..3

  const u16* Wz = W + (size_t)blockIdx.z * wz;

  // T1: bijective XCD swizzle within the z-slice (nwg = 256, divisible by 8)
  const int nwg  = (int)(gridDim.x * gridDim.y);
  const int orig = (int)(blockIdx.y * gridDim.x + blockIdx.x);
  const int swz  = (orig & 7) * (nwg >> 3) + (orig >> 3);
  const int bx   = swz % (int)gridDim.x;
  const int by   = swz / (int)gridDim.x;
  const long mbase = (long)by * 256;
  const long nbase = (long)bx * 256;

  // staging: 512 thr x 16B = 8 KB = 128 rows/round; 2 rounds per matrix half
  const int sR  = tid >> 2;                        // row 0..127 within round
  const int sG8 = (((tid & 3) ^ (sR & 3)) << 3);   // inverse-swizzled k-slot
  const u16* gA = A  + (mbase + sR) * (long)K + sG8;
  const u16* gB = Wz + (nbase + sR) * (long)K + sG8;
  const long rowK = (long)128 * K;

  // fragment reads (swizzled slot; row&3 == n&3 since frag rows step by 16)
  const int n   = lane & 15;
  const int g   = lane >> 4;
  const int sl8 = ((g ^ (n & 3)) << 3);
  const int aoff = (wm*128 + n)*32 + sl8;          // + mf*512
  const int boff = 8192 + (wn*64 + n)*32 + sl8;    // + nf*512

  f32x4 acc[8][4] = {};
  const int NT = K >> 5;   // 64 tiles of BK=32 (even)

#define STAGE_A(bufi, tt) do { \
    u16* d_ = lds + (bufi)*16384 + tid*8; \
    gld_lds16(gA + (long)(tt)*32,        d_); \
    gld_lds16(gA + rowK + (long)(tt)*32, d_ + 4096); } while(0)
#define STAGE_B(bufi, tt) do { \
    u16* d_ = lds + (bufi)*16384 + 8192 + tid*8; \
    gld_lds16(gB + (long)(tt)*32,        d_); \
    gld_lds16(gB + rowK + (long)(tt)*32, d_ + 4096); } while(0)

  // prologue: stage tiles 0,1,2; tiles 0 AND 1 must be landed (tile 0 is
  // computed first and tile 1's frags are prefetched during it); tile 2
  // stays in flight -> vmcnt(4).
  STAGE_A(0, 0); STAGE_B(0, 0);
  STAGE_A(1, 1); STAGE_B(1, 1);
  STAGE_A(2, 2); STAGE_B(2, 2);
  asm volatile("s_waitcnt vmcnt(4)" ::: "memory");
  __builtin_amdgcn_s_barrier();
  asm volatile("" ::: "memory");

  bf16x8 pa0A[4], pb0A[4], a1A[4], pa0B[4], pb0B[4], a1B[4];
  // preload tile 0's a0/b0 (buf 0)
  #pragma unroll
  for (int i = 0; i < 4; i++) pa0A[i] = *(const bf16x8*)&lds[aoff + i*512];
  #pragma unroll
  for (int j = 0; j < 4; j++) pb0A[j] = *(const bf16x8*)&lds[boff + j*512];

  for (int t = 0; t < NT; t += 2) {
    // ---- half A: compute tile t (set A); prefetch tile t+1 frags (set B) --
    {
      const u16* Ab = lds + (t & 3) * 16384;
      const u16* Nb = lds + ((t+1) & 3) * 16384;
      if (t + 3 < NT) STAGE_A((t+3)&3, t+3);
      #pragma unroll
      for (int i = 0; i < 4; i++) a1A[i]  = *(const bf16x8*)&Ab[aoff + (i+4)*512];
      #pragma unroll
      for (int i = 0; i < 4; i++) pa0B[i] = *(const bf16x8*)&Nb[aoff + i*512];
      #pragma unroll
      for (int j = 0; j < 4; j++) pb0B[j] = *(const bf16x8*)&Nb[boff + j*512];
      if (t + 3 < NT) STAGE_B((t+3)&3, t+3);
      __builtin_amdgcn_s_setprio(1);
      #pragma unroll
      for (int i = 0; i < 4; i++)
        #pragma unroll
        for (int j = 0; j < 4; j++)
          acc[i][j] = __builtin_amdgcn_mfma_f32_16x16x32_bf16(pa0A[i], pb0A[j], acc[i][j], 0,0,0);
      #pragma unroll
      for (int i = 0; i < 4; i++)
        #pragma unroll
        for (int j = 0; j < 4; j++)
          acc[i+4][j] = __builtin_amdgcn_mfma_f32_16x16x32_bf16(a1A[i], pb0A[j], acc[i+4][j], 0,0,0);
      __builtin_amdgcn_s_setprio(0);
      // boundary: tile t+2 (prefetched next half) must be landed
      if (t + 3 < NT) { asm volatile("s_waitcnt vmcnt(4)" ::: "memory"); }
      else            { asm volatile("s_waitcnt vmcnt(0)" ::: "memory"); }
      __builtin_amdgcn_s_barrier();
      asm volatile("" ::: "memory");
    }
    // ---- half B: compute tile t+1 (set B); prefetch tile t+2 frags (set A) --
    {
      const int u = t + 1;
      const u16* Ab = lds + (u & 3) * 16384;
      if (u + 3 < NT) STAGE_A((u+3)&3, u+3);
      #pragma unroll
      for (int i = 0; i < 4; i++) a1B[i] = *(const bf16x8*)&Ab[aoff + (i+4)*512];
      if (u + 1 < NT) {
        const u16* Nb = lds + ((u+1) & 3) * 16384;
        #pragma unroll
        for (int i = 0; i < 4; i++) pa0A[i] = *(const bf16x8*)&Nb[aoff + i*512];
        #pragma unroll
        for (int j = 0; j < 4; j++) pb0A[j] = *(const bf16x8*)&Nb[boff + j*512];
      }
      if (u + 3 < NT) STAGE_B((u+3)&3, u+3);
      __builtin_amdgcn_s_setprio(1);
      #pragma unroll
      for (int i = 0; i < 4; i++)
        #pragma unroll
        for (int j = 0; j < 4; j++)
          acc[i][j] = __builtin_amdgcn_mfma_f32_16x16x32_bf16(pa0B[i], pb0B[j], acc[i][j], 0,0,0);
      #pragma unroll
      for (int i = 0; i < 4; i++)
        #pragma unroll
        for (int j = 0; j < 4; j++)
          acc[i+4][j] = __builtin_amdgcn_mfma_f32_16x16x32_bf16(a1B[i], pb0B[j], acc[i+4][j], 0,0,0);
      __builtin_amdgcn_s_setprio(0);
      if (u + 3 < NT) { asm volatile("s_waitcnt vmcnt(4)" ::: "memory"); }
      else            { asm volatile("s_waitcnt vmcnt(0)" ::: "memory"); }
      __builtin_amdgcn_s_barrier();
      asm volatile("" ::: "memory");
    }
  }
#undef STAGE_A
#undef STAGE_B

  // epilogue: same proven C fragment layout (row<-A idx, col<-B idx)
  const int crow0 = g * 4;
  u16*   C16 = (u16*)Cv   + (size_t)blockIdx.z * cz;
  float* C32 = (float*)Cv;
  #pragma unroll
  for (int i = 0; i < 8; i++)
    #pragma unroll
    for (int j = 0; j < 4; j++)
      #pragma unroll
      for (int r = 0; r < 4; r++) {
        const long row = mbase + wm*128 + i*16 + crow0 + r;
        const long col = nbase + wn*64  + j*16 + n;
        if (OUT_BF16) C16[row*N + col] = f2b(acc[i][j][r]);
        else          C32[row*N + col] = acc[i][j][r];
      }
}

// ---------------- RoPE (unchanged) ----------------
__global__ __launch_bounds__(256) void rope_kernel(u16* __restrict__ q, u16* __restrict__ k)
{
  const unsigned idx = blockIdx.x * 256u + threadIdx.x;
  const int d = idx & 63;
  const int h = (idx >> 6) & 15;
  const int t = (idx >> 10) & 2047;
  const int b = idx >> 21;
  const float inv = __expf(-9.210340371976184f * ((float)d * (1.0f/64.0f)));
  const float ang = (float)t * inv;
  float sn, cs;
  sincosf(ang, &sn, &cs);
  const size_t base = ((size_t)(b * TT + t)) * CC + (size_t)h * HD + d;
  const float q0 = b2f(q[base]), q1 = b2f(q[base + 64]);
  q[base]      = f2b(q0*cs - q1*sn);
  q[base + 64] = f2b(q1*cs + q0*sn);
  const float k0 = b2f(k[base]), k1 = b2f(k[base + 64]);
  k[base]      = f2b(k0*cs - k1*sn);
  k[base + 64] = f2b(k1*cs + k0*sn);
}

// ---------------- V transpose (unchanged) ----------------
__global__ __launch_bounds__(256) void transpose_v(const u16* __restrict__ v,
                                                   u16* __restrict__ vt)
{
  __shared__ u16 L[64][136];
  const int tid = threadIdx.x;
  const int t0 = blockIdx.x * 64;
  const int b = blockIdx.y >> 4, h = blockIdx.y & 15;
  #pragma unroll
  for (int it = 0; it < 4; it++) {
    const int row = (tid >> 4) + it*16;
    const int c8 = (tid & 15) * 8;
    *(uint4*)&L[row][c8] = *(const uint4*)(v + ((size_t)(b*TT + t0 + row))*CC + h*HD + c8);
  }
  __syncthreads();
  #pragma unroll
  for (int it = 0; it < 4; it++) {
    const int hd = (tid >> 3) + it*32;
    const int c = (tid & 7) * 8;
    u16 tmp[8];
    #pragma unroll
    for (int j = 0; j < 8; j++) tmp[j] = L[c + j][hd];
    uint4 pk;
    pk.x = (unsigned)tmp[0] | ((unsigned)tmp[1] << 16);
    pk.y = (unsigned)tmp[2] | ((unsigned)tmp[3] << 16);
    pk.z = (unsigned)tmp[4] | ((unsigned)tmp[5] << 16);
    pk.w = (unsigned)tmp[6] | ((unsigned)tmp[7] << 16);
    *(uint4*)(vt + ((size_t)((b*NH + h)*HD + hd))*TT + t0 + c) = pk;
  }
}

// ---------------- MFMA flash attention (unchanged from R4) ----------------
#define PS_ST 72
#define OB_ST 136
__global__ __launch_bounds__(256, 2) void attn_mfma(const u16* __restrict__ q,
                                                    const u16* __restrict__ k,
                                                    const u16* __restrict__ vt,
                                                    u16* __restrict__ y)
{
  __shared__ u16 smem[2*64*128 + 128*64 + 4*32*PS_ST];  // 67584 B -> 2 blocks/CU
  u16* Ks = smem;                    // two 8192-elem K buffers (linear [64][128])
  u16* Vs = smem + 16384;            // one 8192-elem V^T buffer (linear [128][64])
  u16* Ps = smem + 16384 + 8192;     // [4][32][PS_ST], padded (VALU-written)

  const int tid  = threadIdx.x;
  const int lane = tid & 63;
  const int w    = tid >> 6;
  const int n    = lane & 15;
  const int g    = lane >> 4;
  const int k8   = g * 8;
  const int nx   = n & 7;            // read-side swizzle key (row&7 == n&7)
  const int qb   = (int)gridDim.x - 1 - (int)blockIdx.x;  // heavy blocks first
  const int bh   = blockIdx.y;
  const int b = bh >> 4, h = bh & 15;

  const u16* Qg  = q  + (size_t)b*TT*CC + (size_t)h*HD;
  const u16* Kg  = k  + (size_t)b*TT*CC + (size_t)h*HD;
  const u16* Vtg = vt + ((size_t)(b*NH + h)*HD) * TT;
  u16*       Yg  = y  + (size_t)b*TT*CC + (size_t)h*HD;

  // staging geometry: dest linear (tid*16B), global col slot inverse-swizzled
  const int ksrow = tid >> 4;                          // 0..15 (+it*16)
  const int kgc   = ((tid & 15) ^ (ksrow & 7)) * 8;    // elements
  const int vsrow = tid >> 3;                          // 0..31 (+it*32)
  const int vgc   = ((tid & 7) ^ (vsrow & 7)) * 8;
  const u16* KgS = Kg  + (size_t)ksrow*CC + kgc;
  const u16* VgS = Vtg + (size_t)vsrow*TT + vgc;

  bf16x8 qf[2][4];
  #pragma unroll
  for (int mi = 0; mi < 2; mi++)
    #pragma unroll
    for (int s = 0; s < 4; s++)
      qf[mi][s] = *(const bf16x8*)(Qg + (size_t)(qb*128 + w*32 + mi*16 + n)*CC + s*32 + k8);

  f32x4 o[8][2] = {};
  float lrow[2][4] = {};   // per-lane partial row sums

  u16* Psw = Ps + w * 32 * PS_ST;
  const float scale = 0.08838834764831845f;  // 1/sqrt(128)
  const int ktmax = 2*qb + 1;

  // prologue: K(0) -> buf 0 via gld_lds; drain + barrier
  {
    u16* dk = Ks + tid*8;
    #pragma unroll
    for (int it = 0; it < 4; it++)
      gld_lds16(KgS + (size_t)(it*16)*CC, dk + it*2048);
  }
  __syncthreads();

  for (int kt = 0; kt <= ktmax; kt++) {
    const int p = kt & 1;
    // issue V(kt) first (needed at PV, waited at C via vmcnt(4))
    {
      u16* dv = Vs + tid*8;
      #pragma unroll
      for (int it = 0; it < 4; it++)
        gld_lds16(VgS + (size_t)(it*32)*TT + kt*64, dv + it*2048);
    }
    // then K(kt+1) (needed next iter, landed by end-of-iter __syncthreads)
    if (kt < ktmax) {
      u16* dk = Ks + (p^1)*8192 + tid*8;
      #pragma unroll
      for (int it = 0; it < 4; it++)
        gld_lds16(KgS + (size_t)((kt+1)*64 + it*16)*CC, dk + it*2048);
    }

    // S = Q K^T  (32 x 64 per wave), swizzled K reads
    const u16* Kb = Ks + p*8192;
    f32x4 sacc[4][2] = {};
    __builtin_amdgcn_s_setprio(1);
    #pragma unroll
    for (int s = 0; s < 4; s++) {
      #pragma unroll
      for (int j = 0; j < 4; j++) {
        const bf16x8 kb = *(const bf16x8*)&Kb[(16*j + n)*128 + (((s*4 + g) ^ nx) << 3)];
        sacc[j][0] = __builtin_amdgcn_mfma_f32_16x16x32_bf16(qf[0][s], kb, sacc[j][0], 0,0,0);
        sacc[j][1] = __builtin_amdgcn_mfma_f32_16x16x32_bf16(qf[1][s], kb, sacc[j][1], 0,0,0);
      }
    }
    __builtin_amdgcn_s_setprio(0);

    if (kt >= 2*qb) {  // diagonal tiles: causal mask
      #pragma unroll
      for (int mi = 0; mi < 2; mi++)
        #pragma unroll
        for (int j = 0; j < 4; j++)
          #pragma unroll
          for (int r = 0; r < 4; r++) {
            const int kcol = kt*64 + 16*j + n;
            const int qrow = qb*128 + w*32 + mi*16 + 4*g + r;
            if (kcol > qrow) sacc[j][mi][r] = -1e30f;
          }
    }

    // p = exp(s*scale); accumulate row-sum partials; P -> LDS (C->A layout)
    #pragma unroll
    for (int mi = 0; mi < 2; mi++)
      #pragma unroll
      for (int j = 0; j < 4; j++)
        #pragma unroll
        for (int r = 0; r < 4; r++) {
          const float pv = __expf(sacc[j][mi][r] * scale);
          lrow[mi][r] += pv;
          Psw[(mi*16 + 4*g + r)*PS_ST + 16*j + n] = f2b(pv);
        }

    // C: own Psw writes drained (lgkm) + own V loads landed (counted vmcnt);
    // barrier makes all waves' writes visible. Fences on both sides.
    if (kt < ktmax) { asm volatile("s_waitcnt vmcnt(4) lgkmcnt(0)" ::: "memory"); }
    else            { asm volatile("s_waitcnt vmcnt(0) lgkmcnt(0)" ::: "memory"); }
    __builtin_amdgcn_s_barrier();
    asm volatile("" ::: "memory");

    // O += P V, swizzled V reads
    __builtin_amdgcn_s_setprio(1);
    #pragma unroll
    for (int s2 = 0; s2 < 2; s2++) {
      const bf16x8 pa0 = *(const bf16x8*)&Psw[(n)*PS_ST      + s2*32 + k8];
      const bf16x8 pa1 = *(const bf16x8*)&Psw[(16 + n)*PS_ST + s2*32 + k8];
      #pragma unroll
      for (int jo = 0; jo < 8; jo++) {
        const bf16x8 vb = *(const bf16x8*)&Vs[(16*jo + n)*64 + (((s2*4 + g) ^ nx) << 3)];
        o[jo][0] = __builtin_amdgcn_mfma_f32_16x16x32_bf16(pa0, vb, o[jo][0], 0,0,0);
        o[jo][1] = __builtin_amdgcn_mfma_f32_16x16x32_bf16(pa1, vb, o[jo][1], 0,0,0);
      }
    }
    __builtin_amdgcn_s_setprio(0);

    // E: full drain (vmcnt(0): K(kt+1) landed; lgkm: all LDS reads done)
    __syncthreads();
  }

  // final row-sum reduction across the 16 n-lanes (butterfly over col dim)
  #pragma unroll
  for (int mi = 0; mi < 2; mi++)
    #pragma unroll
    for (int r = 0; r < 4; r++) {
      float sv = lrow[mi][r];
      #pragma unroll
      for (int msk = 1; msk <= 8; msk <<= 1) sv += __shfl_xor(sv, msk);
      lrow[mi][r] = sv;
    }

  // epilogue: normalize, bounce through LDS, coalesced bf16 store
  u16* Ob = smem;  // 128 rows x OB_ST
  #pragma unroll
  for (int mi = 0; mi < 2; mi++) {
    float inv[4];
    #pragma unroll
    for (int r = 0; r < 4; r++) inv[r] = 1.0f / lrow[mi][r];
    #pragma unroll
    for (int jo = 0; jo < 8; jo++)
      #pragma unroll
      for (int r = 0; r < 4; r++)
        Ob[(w*32 + mi*16 + 4*g + r)*OB_ST + 16*jo + n] = f2b(o[jo][mi][r] * inv[r]);
  }
  __syncthreads();                         // D: Ob visible before readback
  #pragma unroll
  for (int it = 0; it < 8; it++) {
    const int idx = it*64 + lane;
    const int row = idx >> 4;
    const int ch  = (idx & 15) * 8;
    const uint4 pk = *(const uint4*)&Ob[(w*32 + row)*OB_ST + ch];
    *(uint4*)(Yg + (size_t)(qb*128 + w*32 + row)*CC + ch) = pk;
  }
}

extern "C" void kernel_launch(void* const* d_in, const int* in_sizes, int n_in,
                              void* d_out, int out_size, void* d_ws, size_t ws_size,
                              hipStream_t stream)
{
  const float* x  = (const float*)d_in[0];
  const float* wq = (const float*)d_in[2];
  const float* wk = (const float*)d_in[3];
  const float* wv = (const float*)d_in[4];
  const float* wo = (const float*)d_in[5];

  const size_t NE  = (size_t)BT * CC;
  const size_t NW  = (size_t)CC * CC;
  u16* q  = (u16*)d_ws;
  u16* k  = q  + NE;
  u16* v  = k  + NE;
  u16* y  = v  + NE;
  u16* xb = y  + NE;
  u16* wqb = xb + NE;
  u16* wkb = wqb + NW;   // wq,wk,wv contiguous -> z-stride NW
  u16* wvb = wkb + NW;
  u16* wob = wvb + NW;
  u16* vt  = xb;   // xb dead after V projection; reuse for V^T

  cvt_kernel<<<(int)(NE/8/256), 256, 0, stream>>>(x,  xb,  (int)(NE/8));
  cvt_kernel<<<(int)(NW/8/256), 256, 0, stream>>>(wq, wqb, (int)(NW/8));
  cvt_kernel<<<(int)(NW/8/256), 256, 0, stream>>>(wk, wkb, (int)(NW/8));
  cvt_kernel<<<(int)(NW/8/256), 256, 0, stream>>>(wv, wvb, (int)(NW/8));
  cvt_kernel<<<(int)(NW/8/256), 256, 0, stream>>>(wo, wob, (int)(NW/8));

  // fused QKV projection: one dispatch, blockIdx.z in {0,1,2}
  gemm256<true><<<dim3(8, 32, 3), 512, 0, stream>>>(xb, wqb, q, CC, CC,
                                                    (long)NW, (long)NE);

  rope_kernel<<<(BB*TT*NH*64)/256, 256, 0, stream>>>(q, k);

  transpose_v<<<dim3(TT/64, BB*NH), 256, 0, stream>>>(v, vt);

  attn_mfma<<<dim3(TT/128, BB*NH), 256, 0, stream>>>(q, k, vt, y);

  gemm256<false><<<dim3(8, 32, 1), 512, 0, stream>>>(y, wob, (float*)d_out, CC, CC,
                                                     0L, 0L);
}

// Round 7
// 610.784 us; speedup vs baseline: 1.0124x; 1.0124x over previous
//
#include <hip/hip_runtime.h>
#include <hip/hip_bf16.h>

#define BB 4
#define TT 2048
#define CC 2048
#define NH 16
#define HD 128
#define BT (BB*TT)   // 8192

using u16 = unsigned short;
typedef __bf16 bf16x8 __attribute__((ext_vector_type(8)));
typedef float  f32x4  __attribute__((ext_vector_type(4)));

#define AS1 __attribute__((address_space(1)))
#define AS3 __attribute__((address_space(3)))

__device__ __forceinline__ float b2f(u16 u){ return __uint_as_float(((unsigned)u) << 16); }
__device__ __forceinline__ u16 f2b(float f){
  unsigned u = __float_as_uint(f);
  u += 0x7FFFu + ((u >> 16) & 1u);
  return (u16)(u >> 16);
}
__device__ __forceinline__ void gld_lds16(const u16* g, u16* l){
  __builtin_amdgcn_global_load_lds((const AS1 void*)g, (AS3 void*)l, 16, 0, 0);
}

// ---------------- fp32 -> bf16 convert ----------------
__global__ __launch_bounds__(256) void cvt_kernel(const float* __restrict__ in,
                                                  u16* __restrict__ out, int n8)
{
  const int i = blockIdx.x * 256 + threadIdx.x;
  if (i >= n8) return;
  const float4 a = ((const float4*)in)[2*i];
  const float4 b = ((const float4*)in)[2*i + 1];
  uint4 pk;
  pk.x = (unsigned)f2b(a.x) | ((unsigned)f2b(a.y) << 16);
  pk.y = (unsigned)f2b(a.z) | ((unsigned)f2b(a.w) << 16);
  pk.z = (unsigned)f2b(b.x) | ((unsigned)f2b(b.y) << 16);
  pk.w = (unsigned)f2b(b.z) | ((unsigned)f2b(b.w) << 16);
  ((uint4*)out)[i] = pk;
}

// ---------------- 256x256 ring-4 software-pipelined MFMA GEMM ----------------
// R6 post-mortem: SQ_LDS_BANK_CONFLICT 1.89e7 — the old swizzle key (row&3)
// collapses on even rows (even n -> n&3 in {0,2}: 8 lanes on 2 slots = 4-way
// conflict). Correct key = (row>>1)&3: per consecutive-8-lane group the 4
// even lanes get 4 distinct slots in banks 0-15 and the 4 odd lanes 4
// distinct slots in banks 16-31 -> all 32 banks, conflict-free.
// Key invariance: frag rows step by 16 and staging's second half by +128,
// both ≡ 0 mod 4 after >>1&3 -> one per-lane constant serves all rows.
template<bool OUT_BF16>
__global__ __launch_bounds__(512, 2) void gemm256(const u16* __restrict__ A,
                                                  const u16* __restrict__ W,
                                                  void* __restrict__ Cv,
                                                  int K, int N,
                                                  long wz, long cz)
{
  __shared__ u16 lds[65536];  // 131072 B
  const int tid  = threadIdx.x;
  const int lane = tid & 63;
  const int wid  = tid >> 6;
  const int wm   = wid >> 2;   // 0..1
  const int wn   = wid & 3;    // 0..3

  const u16* Wz = W + (size_t)blockIdx.z * wz;

  // T1: bijective XCD swizzle within the z-slice (nwg = 256, divisible by 8)
  const int nwg  = (int)(gridDim.x * gridDim.y);
  const int orig = (int)(blockIdx.y * gridDim.x + blockIdx.x);
  const int swz  = (orig & 7) * (nwg >> 3) + (orig >> 3);
  const int bx   = swz % (int)gridDim.x;
  const int by   = swz / (int)gridDim.x;
  const long mbase = (long)by * 256;
  const long nbase = (long)bx * 256;

  // staging: 512 thr x 16B = 8 KB = 128 rows/round; 2 rounds per matrix half
  const int sR  = tid >> 2;                              // row 0..127
  const int sG8 = (((tid & 3) ^ ((sR >> 1) & 3)) << 3);  // inverse-swizzled
  const u16* gA = A  + (mbase + sR) * (long)K + sG8;
  const u16* gB = Wz + (nbase + sR) * (long)K + sG8;
  const long rowK = (long)128 * K;

  // fragment reads (swizzled slot; key (row>>1)&3 = (n>>1)&3 across all rows)
  const int n   = lane & 15;
  const int g   = lane >> 4;
  const int sl8 = ((g ^ ((n >> 1) & 3)) << 3);
  const int aoff = (wm*128 + n)*32 + sl8;          // + mf*512
  const int boff = 8192 + (wn*64 + n)*32 + sl8;    // + nf*512

  f32x4 acc[8][4] = {};
  const int NT = K >> 5;   // 64 tiles of BK=32 (even)

#define STAGE_A(bufi, tt) do { \
    u16* d_ = lds + (bufi)*16384 + tid*8; \
    gld_lds16(gA + (long)(tt)*32,        d_); \
    gld_lds16(gA + rowK + (long)(tt)*32, d_ + 4096); } while(0)
#define STAGE_B(bufi, tt) do { \
    u16* d_ = lds + (bufi)*16384 + 8192 + tid*8; \
    gld_lds16(gB + (long)(tt)*32,        d_); \
    gld_lds16(gB + rowK + (long)(tt)*32, d_ + 4096); } while(0)

  // prologue: stage tiles 0,1,2; tiles 0 AND 1 must be landed (tile 0 is
  // computed first and tile 1's frags are prefetched during it); tile 2
  // stays in flight -> vmcnt(4).
  STAGE_A(0, 0); STAGE_B(0, 0);
  STAGE_A(1, 1); STAGE_B(1, 1);
  STAGE_A(2, 2); STAGE_B(2, 2);
  asm volatile("s_waitcnt vmcnt(4)" ::: "memory");
  __builtin_amdgcn_s_barrier();
  asm volatile("" ::: "memory");

  bf16x8 pa0A[4], pb0A[4], a1A[4], pa0B[4], pb0B[4], a1B[4];
  // preload tile 0's a0/b0 (buf 0)
  #pragma unroll
  for (int i = 0; i < 4; i++) pa0A[i] = *(const bf16x8*)&lds[aoff + i*512];
  #pragma unroll
  for (int j = 0; j < 4; j++) pb0A[j] = *(const bf16x8*)&lds[boff + j*512];

  for (int t = 0; t < NT; t += 2) {
    // ---- half A: compute tile t (set A); prefetch tile t+1 frags (set B) --
    {
      const u16* Ab = lds + (t & 3) * 16384;
      const u16* Nb = lds + ((t+1) & 3) * 16384;
      if (t + 3 < NT) STAGE_A((t+3)&3, t+3);
      #pragma unroll
      for (int i = 0; i < 4; i++) a1A[i]  = *(const bf16x8*)&Ab[aoff + (i+4)*512];
      #pragma unroll
      for (int i = 0; i < 4; i++) pa0B[i] = *(const bf16x8*)&Nb[aoff + i*512];
      #pragma unroll
      for (int j = 0; j < 4; j++) pb0B[j] = *(const bf16x8*)&Nb[boff + j*512];
      if (t + 3 < NT) STAGE_B((t+3)&3, t+3);
      __builtin_amdgcn_s_setprio(1);
      #pragma unroll
      for (int i = 0; i < 4; i++)
        #pragma unroll
        for (int j = 0; j < 4; j++)
          acc[i][j] = __builtin_amdgcn_mfma_f32_16x16x32_bf16(pa0A[i], pb0A[j], acc[i][j], 0,0,0);
      #pragma unroll
      for (int i = 0; i < 4; i++)
        #pragma unroll
        for (int j = 0; j < 4; j++)
          acc[i+4][j] = __builtin_amdgcn_mfma_f32_16x16x32_bf16(a1A[i], pb0A[j], acc[i+4][j], 0,0,0);
      __builtin_amdgcn_s_setprio(0);
      if (t + 3 < NT) { asm volatile("s_waitcnt vmcnt(4)" ::: "memory"); }
      else            { asm volatile("s_waitcnt vmcnt(0)" ::: "memory"); }
      __builtin_amdgcn_s_barrier();
      asm volatile("" ::: "memory");
    }
    // ---- half B: compute tile t+1 (set B); prefetch tile t+2 frags (set A) --
    {
      const int u = t + 1;
      const u16* Ab = lds + (u & 3) * 16384;
      if (u + 3 < NT) STAGE_A((u+3)&3, u+3);
      #pragma unroll
      for (int i = 0; i < 4; i++) a1B[i] = *(const bf16x8*)&Ab[aoff + (i+4)*512];
      if (u + 1 < NT) {
        const u16* Nb = lds + ((u+1) & 3) * 16384;
        #pragma unroll
        for (int i = 0; i < 4; i++) pa0A[i] = *(const bf16x8*)&Nb[aoff + i*512];
        #pragma unroll
        for (int j = 0; j < 4; j++) pb0A[j] = *(const bf16x8*)&Nb[boff + j*512];
      }
      if (u + 3 < NT) STAGE_B((u+3)&3, u+3);
      __builtin_amdgcn_s_setprio(1);
      #pragma unroll
      for (int i = 0; i < 4; i++)
        #pragma unroll
        for (int j = 0; j < 4; j++)
          acc[i][j] = __builtin_amdgcn_mfma_f32_16x16x32_bf16(pa0B[i], pb0B[j], acc[i][j], 0,0,0);
      #pragma unroll
      for (int i = 0; i < 4; i++)
        #pragma unroll
        for (int j = 0; j < 4; j++)
          acc[i+4][j] = __builtin_amdgcn_mfma_f32_16x16x32_bf16(a1B[i], pb0B[j], acc[i+4][j], 0,0,0);
      __builtin_amdgcn_s_setprio(0);
      if (u + 3 < NT) { asm volatile("s_waitcnt vmcnt(4)" ::: "memory"); }
      else            { asm volatile("s_waitcnt vmcnt(0)" ::: "memory"); }
      __builtin_amdgcn_s_barrier();
      asm volatile("" ::: "memory");
    }
  }
#undef STAGE_A
#undef STAGE_B

  // epilogue: same proven C fragment layout (row<-A idx, col<-B idx)
  const int crow0 = g * 4;
  u16*   C16 = (u16*)Cv   + (size_t)blockIdx.z * cz;
  float* C32 = (float*)Cv;
  #pragma unroll
  for (int i = 0; i < 8; i++)
    #pragma unroll
    for (int j = 0; j < 4; j++)
      #pragma unroll
      for (int r = 0; r < 4; r++) {
        const long row = mbase + wm*128 + i*16 + crow0 + r;
        const long col = nbase + wn*64  + j*16 + n;
        if (OUT_BF16) C16[row*N + col] = f2b(acc[i][j][r]);
        else          C32[row*N + col] = acc[i][j][r];
      }
}

// ---------------- RoPE (unchanged) ----------------
__global__ __launch_bounds__(256) void rope_kernel(u16* __restrict__ q, u16* __restrict__ k)
{
  const unsigned idx = blockIdx.x * 256u + threadIdx.x;
  const int d = idx & 63;
  const int h = (idx >> 6) & 15;
  const int t = (idx >> 10) & 2047;
  const int b = idx >> 21;
  const float inv = __expf(-9.210340371976184f * ((float)d * (1.0f/64.0f)));
  const float ang = (float)t * inv;
  float sn, cs;
  sincosf(ang, &sn, &cs);
  const size_t base = ((size_t)(b * TT + t)) * CC + (size_t)h * HD + d;
  const float q0 = b2f(q[base]), q1 = b2f(q[base + 64]);
  q[base]      = f2b(q0*cs - q1*sn);
  q[base + 64] = f2b(q1*cs + q0*sn);
  const float k0 = b2f(k[base]), k1 = b2f(k[base + 64]);
  k[base]      = f2b(k0*cs - k1*sn);
  k[base + 64] = f2b(k1*cs + k0*sn);
}

// ---------------- V transpose (unchanged) ----------------
__global__ __launch_bounds__(256) void transpose_v(const u16* __restrict__ v,
                                                   u16* __restrict__ vt)
{
  __shared__ u16 L[64][136];
  const int tid = threadIdx.x;
  const int t0 = blockIdx.x * 64;
  const int b = blockIdx.y >> 4, h = blockIdx.y & 15;
  #pragma unroll
  for (int it = 0; it < 4; it++) {
    const int row = (tid >> 4) + it*16;
    const int c8 = (tid & 15) * 8;
    *(uint4*)&L[row][c8] = *(const uint4*)(v + ((size_t)(b*TT + t0 + row))*CC + h*HD + c8);
  }
  __syncthreads();
  #pragma unroll
  for (int it = 0; it < 4; it++) {
    const int hd = (tid >> 3) + it*32;
    const int c = (tid & 7) * 8;
    u16 tmp[8];
    #pragma unroll
    for (int j = 0; j < 8; j++) tmp[j] = L[c + j][hd];
    uint4 pk;
    pk.x = (unsigned)tmp[0] | ((unsigned)tmp[1] << 16);
    pk.y = (unsigned)tmp[2] | ((unsigned)tmp[3] << 16);
    pk.z = (unsigned)tmp[4] | ((unsigned)tmp[5] << 16);
    pk.w = (unsigned)tmp[6] | ((unsigned)tmp[7] << 16);
    *(uint4*)(vt + ((size_t)((b*NH + h)*HD + hd))*TT + t0 + c) = pk;
  }
}

// ---------------- MFMA flash attention, swapped-QK in-register softmax ----
// R7 (T12): compute S^T = mfma(K, Q) so lane (n,g) holds
// P[k=16j+4g+r][q=mi*16+n] — q is lane-indexed, so P feeds PV's A operand
// WITHOUT the LDS bounce. k-realignment to the A-frag layout (k=8g+e) via
// 16 v_cvt_pk_bf16_f32 packs + 32 intra-wave shfl:
//   pa[mi][s2].word[w] = shfl(P2[2s2+(g>>1)][mi][w&1],
//                             n + 16*((2g+(w>>1))&3)),  select by (g&2).
// (index identity: k = s2*32+8g+2w{+1} = 16j+4g'+2h with j=2s2+(g>>1),
//  g'=(2g+(w>>1))&3, h=w&1 — verified on 4 samples.)
// This deletes barrier C, 32 ds_writes, and the P buffer; V is now
// double-buffered like K -> ONE barrier per tile (end __syncthreads =
// vmcnt(0)+lgkm(0): next tile's K/V landed, all reads of current buf done).
// Row-sums: lrow[mi] is lane-local over (j,r); reduce over g (shfl_xor
// 16/32); epilogue fetches 1/rowsum via shfl from lane 4g+r.
// cvt_pk_bf16_f32 is RNE like f2b -> P values bit-identical.
#define OB_ST 136
__global__ __launch_bounds__(256, 2) void attn_mfma(const u16* __restrict__ q,
                                                    const u16* __restrict__ k,
                                                    const u16* __restrict__ vt,
                                                    u16* __restrict__ y)
{
  __shared__ u16 smem[4*64*128];     // 65536 B -> 2 blocks/CU
  u16* Ks = smem;                    // [2][64][128] linear, swizzled cols
  u16* Vs = smem + 16384;            // [2][128][64] linear, swizzled cols

  const int tid  = threadIdx.x;
  const int lane = tid & 63;
  const int w    = tid >> 6;
  const int n    = lane & 15;
  const int g    = lane >> 4;
  const int k8   = g * 8;
  const int nx   = n & 7;            // read-side swizzle key (row&7 == n&7)
  const int qb   = (int)gridDim.x - 1 - (int)blockIdx.x;  // heavy blocks first
  const int bh   = blockIdx.y;
  const int b = bh >> 4, h = bh & 15;

  const u16* Qg  = q  + (size_t)b*TT*CC + (size_t)h*HD;
  const u16* Kg  = k  + (size_t)b*TT*CC + (size_t)h*HD;
  const u16* Vtg = vt + ((size_t)(b*NH + h)*HD) * TT;
  u16*       Yg  = y  + (size_t)b*TT*CC + (size_t)h*HD;

  // staging geometry: dest linear (tid*16B), global col slot inverse-swizzled
  const int ksrow = tid >> 4;                          // 0..15 (+it*16)
  const int kgc   = ((tid & 15) ^ (ksrow & 7)) * 8;    // elements
  const int vsrow = tid >> 3;                          // 0..31 (+it*32)
  const int vgc   = ((tid & 7) ^ (vsrow & 7)) * 8;
  const u16* KgS = Kg  + (size_t)ksrow*CC + kgc;
  const u16* VgS = Vtg + (size_t)vsrow*TT + vgc;

  bf16x8 qf[2][4];
  #pragma unroll
  for (int mi = 0; mi < 2; mi++)
    #pragma unroll
    for (int s = 0; s < 4; s++)
      qf[mi][s] = *(const bf16x8*)(Qg + (size_t)(qb*128 + w*32 + mi*16 + n)*CC + s*32 + k8);

  f32x4 o[8][2] = {};
  float lrow[2] = {};   // lane-local row sums (q = mi*16 + n)

  const float scale = 0.08838834764831845f;  // 1/sqrt(128)
  const int ktmax = 2*qb + 1;

  // prologue: K(0), V(0) -> buf 0 via gld_lds; drain + barrier
  {
    u16* dk = Ks + tid*8;
    #pragma unroll
    for (int it = 0; it < 4; it++)
      gld_lds16(KgS + (size_t)(it*16)*CC, dk + it*2048);
    u16* dv = Vs + tid*8;
    #pragma unroll
    for (int it = 0; it < 4; it++)
      gld_lds16(VgS + (size_t)(it*32)*TT, dv + it*2048);
  }
  __syncthreads();

  for (int kt = 0; kt <= ktmax; kt++) {
    const int p = kt & 1;
    // prefetch tile kt+1 (K and V) into buf p^1; full tile of compute covers it
    if (kt < ktmax) {
      u16* dk = Ks + (p^1)*8192 + tid*8;
      #pragma unroll
      for (int it = 0; it < 4; it++)
        gld_lds16(KgS + (size_t)((kt+1)*64 + it*16)*CC, dk + it*2048);
      u16* dv = Vs + (p^1)*8192 + tid*8;
      #pragma unroll
      for (int it = 0; it < 4; it++)
        gld_lds16(VgS + (size_t)(it*32)*TT + (kt+1)*64, dv + it*2048);
    }

    // S^T = K Q^T  (swapped operands: D rows = kv, cols = q)
    const u16* Kb = Ks + p*8192;
    f32x4 sacc[4][2] = {};
    __builtin_amdgcn_s_setprio(1);
    #pragma unroll
    for (int s = 0; s < 4; s++) {
      #pragma unroll
      for (int j = 0; j < 4; j++) {
        const bf16x8 kb = *(const bf16x8*)&Kb[(16*j + n)*128 + (((s*4 + g) ^ nx) << 3)];
        sacc[j][0] = __builtin_amdgcn_mfma_f32_16x16x32_bf16(kb, qf[0][s], sacc[j][0], 0,0,0);
        sacc[j][1] = __builtin_amdgcn_mfma_f32_16x16x32_bf16(kb, qf[1][s], sacc[j][1], 0,0,0);
      }
    }
    __builtin_amdgcn_s_setprio(0);

    if (kt >= 2*qb) {  // diagonal tiles: causal mask (k in regs, q in lanes)
      #pragma unroll
      for (int mi = 0; mi < 2; mi++)
        #pragma unroll
        for (int j = 0; j < 4; j++)
          #pragma unroll
          for (int r = 0; r < 4; r++) {
            const int kcol = kt*64 + 16*j + 4*g + r;
            const int qrow = qb*128 + w*32 + mi*16 + n;
            if (kcol > qrow) sacc[j][mi][r] = -1e30f;
          }
    }

    // p = exp(s*scale); lane-local row-sum; pack to bf16 pairs (RNE)
    unsigned P2[4][2][2];
    #pragma unroll
    for (int j = 0; j < 4; j++)
      #pragma unroll
      for (int mi = 0; mi < 2; mi++) {
        const float e0 = __expf(sacc[j][mi][0] * scale);
        const float e1 = __expf(sacc[j][mi][1] * scale);
        const float e2 = __expf(sacc[j][mi][2] * scale);
        const float e3 = __expf(sacc[j][mi][3] * scale);
        lrow[mi] += (e0 + e1) + (e2 + e3);
        asm("v_cvt_pk_bf16_f32 %0, %1, %2" : "=v"(P2[j][mi][0]) : "v"(e0), "v"(e1));
        asm("v_cvt_pk_bf16_f32 %0, %1, %2" : "=v"(P2[j][mi][1]) : "v"(e2), "v"(e3));
      }

    // realign k to A-frag layout via intra-wave shfl (no LDS, no barrier)
    uint4 pa[2][2];   // [mi][s2], each = bf16x8 with k = s2*32 + 8g + 0..7
    #pragma unroll
    for (int mi = 0; mi < 2; mi++)
      #pragma unroll
      for (int s2 = 0; s2 < 2; s2++) {
        unsigned wv[4];
        #pragma unroll
        for (int ww = 0; ww < 4; ww++) {
          const int src = n + 16*((2*g + (ww>>1)) & 3);
          const unsigned lo = __shfl(P2[2*s2    ][mi][ww & 1], src);
          const unsigned hi = __shfl(P2[2*s2 + 1][mi][ww & 1], src);
          wv[ww] = (g & 2) ? hi : lo;
        }
        pa[mi][s2].x = wv[0]; pa[mi][s2].y = wv[1];
        pa[mi][s2].z = wv[2]; pa[mi][s2].w = wv[3];
      }

    // O += P V (V(kt) landed at previous iteration-end barrier)
    const u16* Vb = Vs + p*8192;
    __builtin_amdgcn_s_setprio(1);
    #pragma unroll
    for (int s2 = 0; s2 < 2; s2++) {
      const bf16x8 pa0 = *(const bf16x8*)&pa[0][s2];
      const bf16x8 pa1 = *(const bf16x8*)&pa[1][s2];
      #pragma unroll
      for (int jo = 0; jo < 8; jo++) {
        const bf16x8 vb = *(const bf16x8*)&Vb[(16*jo + n)*64 + (((s2*4 + g) ^ nx) << 3)];
        o[jo][0] = __builtin_amdgcn_mfma_f32_16x16x32_bf16(pa0, vb, o[jo][0], 0,0,0);
        o[jo][1] = __builtin_amdgcn_mfma_f32_16x16x32_bf16(pa1, vb, o[jo][1], 0,0,0);
      }
    }
    __builtin_amdgcn_s_setprio(0);

    // E: vmcnt(0) (K/V(kt+1) landed) + lgkm + barrier; also protects buf p^1
    // from being overwritten while slow waves still read it next iteration.
    __syncthreads();
  }

  // row-sum reduction across the 4 g-quarters (duplicates of q = mi*16+n)
  #pragma unroll
  for (int mi = 0; mi < 2; mi++) {
    float sv = lrow[mi];
    sv += __shfl_xor(sv, 16);
    sv += __shfl_xor(sv, 32);
    lrow[mi] = sv;
  }

  // epilogue: normalize, bounce through LDS, coalesced bf16 store
  u16* Ob = smem;  // 128 rows x OB_ST (17408 u16 <= 32768)
  #pragma unroll
  for (int mi = 0; mi < 2; mi++) {
    float inv[4];
    #pragma unroll
    for (int r = 0; r < 4; r++) inv[r] = 1.0f / __shfl(lrow[mi], 4*g + r);
    #pragma unroll
    for (int jo = 0; jo < 8; jo++)
      #pragma unroll
      for (int r = 0; r < 4; r++)
        Ob[(w*32 + mi*16 + 4*g + r)*OB_ST + 16*jo + n] = f2b(o[jo][mi][r] * inv[r]);
  }
  __syncthreads();                         // D: Ob visible before readback
  #pragma unroll
  for (int it = 0; it < 8; it++) {
    const int idx = it*64 + lane;
    const int row = idx >> 4;
    const int ch  = (idx & 15) * 8;
    const uint4 pk = *(const uint4*)&Ob[(w*32 + row)*OB_ST + ch];
    *(uint4*)(Yg + (size_t)(qb*128 + w*32 + row)*CC + ch) = pk;
  }
}

extern "C" void kernel_launch(void* const* d_in, const int* in_sizes, int n_in,
                              void* d_out, int out_size, void* d_ws, size_t ws_size,
                              hipStream_t stream)
{
  const float* x  = (const float*)d_in[0];
  const float* wq = (const float*)d_in[2];
  const float* wk = (const float*)d_in[3];
  const float* wv = (const float*)d_in[4];
  const float* wo = (const float*)d_in[5];

  const size_t NE  = (size_t)BT * CC;
  const size_t NW  = (size_t)CC * CC;
  u16* q  = (u16*)d_ws;
  u16* k  = q  + NE;
  u16* v  = k  + NE;
  u16* y  = v  + NE;
  u16* xb = y  + NE;
  u16* wqb = xb + NE;
  u16* wkb = wqb + NW;   // wq,wk,wv contiguous -> z-stride NW
  u16* wvb = wkb + NW;
  u16* wob = wvb + NW;
  u16* vt  = xb;   // xb dead after V projection; reuse for V^T

  cvt_kernel<<<(int)(NE/8/256), 256, 0, stream>>>(x,  xb,  (int)(NE/8));
  cvt_kernel<<<(int)(NW/8/256), 256, 0, stream>>>(wq, wqb, (int)(NW/8));
  cvt_kernel<<<(int)(NW/8/256), 256, 0, stream>>>(wk, wkb, (int)(NW/8));
  cvt_kernel<<<(int)(NW/8/256), 256, 0, stream>>>(wv, wvb, (int)(NW/8));
  cvt_kernel<<<(int)(NW/8/256), 256, 0, stream>>>(wo, wob, (int)(NW/8));

  // fused QKV projection: one dispatch, blockIdx.z in {0,1,2}
  gemm256<true><<<dim3(8, 32, 3), 512, 0, stream>>>(xb, wqb, q, CC, CC,
                                                    (long)NW, (long)NE);

  rope_kernel<<<(BB*TT*NH*64)/256, 256, 0, stream>>>(q, k);

  transpose_v<<<dim3(TT/64, BB*NH), 256, 0, stream>>>(v, vt);

  attn_mfma<<<dim3(TT/128, BB*NH), 256, 0, stream>>>(q, k, vt, y);

  gemm256<false><<<dim3(8, 32, 1), 512, 0, stream>>>(y, wob, (float*)d_out, CC, CC,
                                                     0L, 0L);
}